// Round 1
// baseline (265.479 us; speedup 1.0000x reference)
//
#include <hip/hip_runtime.h>

#define HH 480
#define WW 640
#define NC 3
#define NVX 128           // W/SKIP
#define NVY 96            // H/SKIP
#define NV (NVX * NVY)    // 12288
#define NBX 80
#define NBY 60
#define NB (NBX * NBY)    // 4800
#define CHUNK 512
#define NCHUNK (NV / CHUNK)          // 24
#define BINBLOCKS ((NB + 255) / 256) // 19

// ---------------- kernel 1: gather per-point data ----------------
__global__ void precompute_pts(const int* __restrict__ label,
                               const float* __restrict__ vert,
                               float4* __restrict__ pts,
                               int* __restrict__ counts) {
    int i = blockIdx.x * 256 + threadIdx.x;
    if (i >= NV) return;
    int iy = i >> 7;          // / NVX
    int ix = i & (NVX - 1);   // % NVX
    int vy = 5 * iy, vx = 5 * ix;
    int pix = vy * WW + vx;
    int vl = label[pix];
    const float* base = vert + (size_t)(vl * 3) * HH * WW + pix;
    float4 p;
    p.x = base[0];                       // ux
    p.y = base[(size_t)HH * WW];         // uy
    p.z = base[(size_t)2 * HH * WW];     // dist
    p.w = __int_as_float(vl);
    pts[i] = p;
    atomicAdd(&counts[vl], 1);
}

// ---------------- kernel 2: voting ----------------
// hough points at d_out+18 (3*NB floats, row 0 stays zero); dsum = 2*NB floats.
__global__ void vote(const float4* __restrict__ pts,
                     float* __restrict__ hough,
                     float* __restrict__ dsum) {
    __shared__ float4 sh[256];
    const int tid = threadIdx.x;
    const int b = blockIdx.x * 256 + tid;
    const bool vb = (b < NB);
    float bxf = 0.f, byf = 0.f;
    if (vb) {
        bxf = (float)(4 + 8 * (b % NBX));
        byf = (float)(4 + 8 * (b / NBX));
    }
    const int p0 = blockIdx.y * CHUNK;
    float h1 = 0.f, h2 = 0.f, d1 = 0.f, d2 = 0.f;

    for (int t = 0; t < CHUNK; t += 256) {
        sh[tid] = pts[p0 + t + tid];
        __syncthreads();
        if (vb) {
#pragma unroll 4
            for (int j = 0; j < 256; ++j) {
                float4 p = sh[j];
                int pi = p0 + t + j;
                float vxf = (float)(5 * (pi & (NVX - 1)));
                float vyf = (float)(5 * (pi >> 7));
                // exact-order IEEE ops to match the np fp32 reference bitwise
                float ddx = __fsub_rn(bxf, vxf);
                float ddy = __fsub_rn(byf, vyf);
                float nx = __fadd_rn(
                    __fadd_rn(__fmul_rn(ddx, ddx), __fmul_rn(ddy, ddy)), 1e-6f);
                float inv = __fdiv_rn(1.0f, __fsqrt_rn(nx));
                float dot = __fadd_rn(__fmul_rn(ddx, p.x), __fmul_rn(ddy, p.y));
                float cosv = __fmul_rn(dot, inv);
                if (cosv > 0.5f) {
                    int vl = __float_as_int(p.w);
                    if (vl == 1) { h1 += 1.0f; d1 += p.z; }
                    else if (vl == 2) { h2 += 1.0f; d2 += p.z; }
                }
            }
        }
        __syncthreads();
    }
    if (vb) {
        atomicAdd(&hough[NB + b], h1);
        atomicAdd(&hough[2 * NB + b], h2);
        atomicAdd(&dsum[b], d1);
        atomicAdd(&dsum[NB + b], d2);
    }
}

// ---------------- kernel 3: argmax + ROI math ----------------
__global__ void finalize(const float* __restrict__ hough,
                         const float* __restrict__ dsum,
                         const int* __restrict__ counts,
                         const float* __restrict__ meta,
                         const float* __restrict__ extents,
                         float* __restrict__ rois) {
    __shared__ float sval[256];
    __shared__ int sidx[256];
    const int tid = threadIdx.x;
    for (int c = 0; c < NC; ++c) {
        float best = -1.0f;  // hough >= 0 always
        int bi = 0;
        for (int i = tid; i < NB; i += 256) {
            float v = hough[c * NB + i];
            if (v > best) { best = v; bi = i; }  // strict > keeps first max in increasing scan
        }
        sval[tid] = best; sidx[tid] = bi;
        __syncthreads();
        for (int s = 128; s > 0; s >>= 1) {
            if (tid < s) {
                float vo = sval[tid + s]; int io = sidx[tid + s];
                if (vo > sval[tid] || (vo == sval[tid] && io < sidx[tid])) {
                    sval[tid] = vo; sidx[tid] = io;
                }
            }
            __syncthreads();
        }
        if (tid == 0) {
            float votes = sval[0];
            int peak = sidx[0];
            float ds = (c == 0) ? 0.0f : dsum[(c - 1) * NB + peak];
            float depth = __fdiv_rn(ds, fmaxf(votes, 1.0f));
            float cx = (float)(4 + 8 * (peak % NBX));
            float cy = (float)(4 + 8 * (peak / NBX));
            float cnt = (float)counts[c];
            float score = __fdiv_rn(votes, fmaxf(cnt, 1.0f));
            int valid = (cnt > 5.0f) && (score > 0.3f);
            float fx = meta[0], fy = meta[4];
            float e0 = extents[c * 3 + 0];
            float e1 = extents[c * 3 + 1];
            float e2 = extents[c * 3 + 2];
            float diag = __fsqrt_rn(__fadd_rn(
                __fadd_rn(__fmul_rn(e0, e0), __fmul_rn(e1, e1)), __fmul_rn(e2, e2)));
            float sz = fmaxf(fabsf(depth), 0.001f);
            float bw = __fdiv_rn(fabsf(__fmul_rn(diag, fx)), sz);
            float bh = __fdiv_rn(fabsf(__fmul_rn(diag, fy)), sz);
            rois[c * 6 + 0] = (float)c;
            rois[c * 6 + 1] = cx - bw * 0.5f;
            rois[c * 6 + 2] = cy - bh * 0.5f;
            rois[c * 6 + 3] = cx + bw * 0.5f;
            rois[c * 6 + 4] = cy + bh * 0.5f;
            rois[c * 6 + 5] = valid ? score : 0.0f;
        }
        __syncthreads();
    }
}

extern "C" void kernel_launch(void* const* d_in, const int* in_sizes, int n_in,
                              void* d_out, int out_size, void* d_ws, size_t ws_size,
                              hipStream_t stream) {
    const int* label = (const int*)d_in[0];
    const float* vert = (const float*)d_in[1];
    const float* meta = (const float*)d_in[2];
    const float* extents = (const float*)d_in[3];
    float* out = (float*)d_out;

    float4* pts = (float4*)d_ws;
    char* ws2 = (char*)d_ws + (size_t)NV * sizeof(float4);
    float* dsum = (float*)ws2;
    int* counts = (int*)(ws2 + 2 * NB * sizeof(float));

    // zero: whole output (hough accumulated in place, row 0 stays 0) + dsum + counts
    hipMemsetAsync(d_out, 0, (size_t)out_size * sizeof(float), stream);
    hipMemsetAsync(ws2, 0, 2 * NB * sizeof(float) + NC * sizeof(int), stream);

    precompute_pts<<<NV / 256, 256, 0, stream>>>(label, vert, pts, counts);
    vote<<<dim3(BINBLOCKS, NCHUNK), 256, 0, stream>>>(pts, out + 18, dsum);
    finalize<<<1, 256, 0, stream>>>(out + 18, dsum, counts, meta, extents, out);
}

// Round 2
// 102.988 us; speedup vs baseline: 2.5778x; 2.5778x over previous
//
#include <hip/hip_runtime.h>

#define HH 480
#define WW 640
#define NC 3
#define NVX 128           // W/SKIP
#define NVY 96            // H/SKIP
#define NV (NVX * NVY)    // 12288
#define NBX 80
#define NBY 60
#define NB (NBX * NBY)    // 4800
#define CHUNK 128
#define NCHUNK (NV / CHUNK)          // 96
#define BINBLOCKS ((NB + 255) / 256) // 19
#define NPB 96                       // precompute blocks (96*256 = 24576 threads)

// ---------------- kernel 1: gather per-point data + zero accumulators ----------------
// ptsA[i] = (vxf, vyf, ux, uy) ; ptsB[i] = (z1, z2, c1, c2)
//   c1 = (vl==1), c2 = (vl==2), z1 = c1?dist:0, z2 = c2?dist:0
// Also zeroes hough (3*NB in d_out) and dsum (2*NB in ws), and writes per-block
// label histograms (no global atomics, no memset dependency).
__global__ void precompute_pts(const int* __restrict__ label,
                               const float* __restrict__ vert,
                               float4* __restrict__ ptsA,
                               float4* __restrict__ ptsB,
                               float* __restrict__ hough,
                               float* __restrict__ dsum,
                               float* __restrict__ blockCounts) {
    __shared__ int hist[NC];
    const int tid = threadIdx.x;
    if (tid < NC) hist[tid] = 0;
    __syncthreads();
    const int i = blockIdx.x * 256 + tid;
    if (i < NV) {
        int iy = i >> 7;          // / NVX
        int ix = i & (NVX - 1);   // % NVX
        int pix = (5 * iy) * WW + 5 * ix;
        int vl = label[pix];
        const float* base = vert + (size_t)(vl * 3) * HH * WW + pix;
        float ux = base[0];
        float uy = base[(size_t)HH * WW];
        float dist = base[(size_t)2 * HH * WW];
        ptsA[i] = make_float4((float)(5 * ix), (float)(5 * iy), ux, uy);
        float c1 = (vl == 1) ? 1.0f : 0.0f;
        float c2 = (vl == 2) ? 1.0f : 0.0f;
        ptsB[i] = make_float4((vl == 1) ? dist : 0.0f,
                              (vl == 2) ? dist : 0.0f, c1, c2);
        atomicAdd(&hist[vl], 1);
    }
    // zero the atomic accumulation targets (24576 threads >= 14400 and 9600)
    if (i < NC * NB) hough[i] = 0.0f;
    if (i < 2 * NB) dsum[i] = 0.0f;
    __syncthreads();
    if (tid < NC) blockCounts[blockIdx.x * NC + tid] = (float)hist[tid];
}

// ---------------- kernel 2: voting ----------------
// Fast path: rsq + FMA. Decisions within 1e-4 of the 0.5 threshold are
// recomputed with the reference's exact IEEE op sequence -> bit-identical
// hough vs the np fp32 reference (approx-path error bound ~1.5e-6).
__global__ void vote(const float4* __restrict__ ptsA,
                     const float4* __restrict__ ptsB,
                     float* __restrict__ hough,
                     float* __restrict__ dsum) {
    __shared__ float4 shA[CHUNK];
    __shared__ float4 shB[CHUNK];
    const int tid = threadIdx.x;
    const int p0 = blockIdx.y * CHUNK;
    if (tid < CHUNK) shA[tid] = ptsA[p0 + tid];
    else             shB[tid - CHUNK] = ptsB[p0 + tid - CHUNK];

    const int b = blockIdx.x * 256 + tid;
    const float bxf = (float)(4 + 8 * (b % NBX));
    const float byf = (float)(4 + 8 * (b / NBX));
    float h1 = 0.f, h2 = 0.f, d1 = 0.f, d2 = 0.f;
    __syncthreads();

#pragma unroll 4
    for (int j = 0; j < CHUNK; ++j) {
        float4 a = shA[j];   // vx, vy, ux, uy
        float4 q = shB[j];   // z1, z2, c1, c2
        float ddx = bxf - a.x;
        float ddy = byf - a.y;
        float nx  = __builtin_fmaf(ddx, ddx, __builtin_fmaf(ddy, ddy, 1e-6f));
        float inv = __builtin_amdgcn_rsqf(nx);                 // v_rsq_f32
        float dot = __builtin_fmaf(ddx, a.z, ddy * a.w);
        float t   = dot * inv - 0.5f;
        if (fabsf(t) < 1e-4f) {
            // exact reference op sequence (rare: ~1e-5 of pairs)
            float nxe  = __fadd_rn(__fadd_rn(__fmul_rn(ddx, ddx),
                                             __fmul_rn(ddy, ddy)), 1e-6f);
            float inve = __fdiv_rn(1.0f, __fsqrt_rn(nxe));
            float dote = __fadd_rn(__fmul_rn(ddx, a.z), __fmul_rn(ddy, a.w));
            t = __fmul_rn(dote, inve) - 0.5f;
        }
        float m = (t > 0.0f) ? 1.0f : 0.0f;
        d1 = __builtin_fmaf(m, q.x, d1);   // m*z1 exact -> single-rounded add
        d2 = __builtin_fmaf(m, q.y, d2);
        h1 = __builtin_fmaf(m, q.z, h1);   // exact small-int arithmetic
        h2 = __builtin_fmaf(m, q.w, h2);
    }
    if (b < NB) {
        atomicAdd(&hough[NB + b], h1);
        atomicAdd(&hough[2 * NB + b], h2);
        atomicAdd(&dsum[b], d1);
        atomicAdd(&dsum[NB + b], d2);
    }
}

// ---------------- kernel 3: argmax + ROI math (one block per class) ----------------
__global__ void finalize(const float* __restrict__ hough,
                         const float* __restrict__ dsum,
                         const float* __restrict__ blockCounts,
                         const float* __restrict__ meta,
                         const float* __restrict__ extents,
                         float* __restrict__ rois) {
    __shared__ unsigned long long skey[256];
    __shared__ float scnt[256];
    const int tid = threadIdx.x;
    const int c = blockIdx.x;

    float cnt = 0.0f;
    for (int i = tid; i < NPB; i += 256) cnt += blockCounts[i * NC + c];
    scnt[tid] = cnt;

    // packed (value_bits, NB-1-i): max value wins, ties -> smallest index
    unsigned long long best = 0ull;
    for (int i = tid; i < NB; i += 256) {
        float v = hough[c * NB + i];
        unsigned long long key =
            ((unsigned long long)__float_as_uint(v) << 32) |
            (unsigned long long)(unsigned)(NB - 1 - i);
        if (key > best) best = key;
    }
    skey[tid] = best;
    __syncthreads();
    for (int s = 128; s > 0; s >>= 1) {
        if (tid < s) {
            if (skey[tid + s] > skey[tid]) skey[tid] = skey[tid + s];
            scnt[tid] += scnt[tid + s];
        }
        __syncthreads();
    }
    if (tid == 0) {
        float votes = __uint_as_float((unsigned)(skey[0] >> 32));
        int peak = NB - 1 - (int)(skey[0] & 0xffffffffull);
        float ds = (c == 0) ? 0.0f : dsum[(c - 1) * NB + peak];
        float depth = __fdiv_rn(ds, fmaxf(votes, 1.0f));
        float cx = (float)(4 + 8 * (peak % NBX));
        float cy = (float)(4 + 8 * (peak / NBX));
        float cntf = scnt[0];
        float score = __fdiv_rn(votes, fmaxf(cntf, 1.0f));
        int valid = (cntf > 5.0f) && (score > 0.3f);
        float fx = meta[0], fy = meta[4];
        float e0 = extents[c * 3 + 0];
        float e1 = extents[c * 3 + 1];
        float e2 = extents[c * 3 + 2];
        float diag = __fsqrt_rn(__fadd_rn(
            __fadd_rn(__fmul_rn(e0, e0), __fmul_rn(e1, e1)), __fmul_rn(e2, e2)));
        float sz = fmaxf(fabsf(depth), 0.001f);
        float bw = __fdiv_rn(fabsf(__fmul_rn(diag, fx)), sz);
        float bh = __fdiv_rn(fabsf(__fmul_rn(diag, fy)), sz);
        rois[c * 6 + 0] = (float)c;
        rois[c * 6 + 1] = cx - bw * 0.5f;
        rois[c * 6 + 2] = cy - bh * 0.5f;
        rois[c * 6 + 3] = cx + bw * 0.5f;
        rois[c * 6 + 4] = cy + bh * 0.5f;
        rois[c * 6 + 5] = valid ? score : 0.0f;
    }
}

extern "C" void kernel_launch(void* const* d_in, const int* in_sizes, int n_in,
                              void* d_out, int out_size, void* d_ws, size_t ws_size,
                              hipStream_t stream) {
    const int* label = (const int*)d_in[0];
    const float* vert = (const float*)d_in[1];
    const float* meta = (const float*)d_in[2];
    const float* extents = (const float*)d_in[3];
    float* out = (float*)d_out;

    char* ws = (char*)d_ws;
    float4* ptsA = (float4*)ws;                                   // 196608 B
    float4* ptsB = (float4*)(ws + (size_t)NV * 16);               // 196608 B
    float* dsum = (float*)(ws + (size_t)2 * NV * 16);             // 38400 B
    float* blockCounts = (float*)(ws + (size_t)2 * NV * 16 + 2 * NB * 4); // 1152 B

    float* hough = out + NC * 6;  // 3*NB floats; rois occupy out[0..17]

    precompute_pts<<<NPB, 256, 0, stream>>>(label, vert, ptsA, ptsB,
                                            hough, dsum, blockCounts);
    vote<<<dim3(BINBLOCKS, NCHUNK), 256, 0, stream>>>(ptsA, ptsB, hough, dsum);
    finalize<<<NC, 256, 0, stream>>>(hough, dsum, blockCounts, meta, extents, out);
}

// Round 3
// 101.287 us; speedup vs baseline: 2.6211x; 1.0168x over previous
//
#include <hip/hip_runtime.h>

#define HH 480
#define WW 640
#define NC 3
#define NVX 128           // W/SKIP
#define NVY 96            // H/SKIP
#define NV (NVX * NVY)    // 12288
#define NBX 80
#define NBY 60
#define NB (NBX * NBY)    // 4800
#define NPB 48                       // precompute blocks (48*256 = 12288 = NV)
#define BINBLOCKS ((NB + 255) / 256) // 19

// ---------------- kernel 1: gather + per-block stable compaction (vl>0 only) ----------------
// Bucket b (48 buckets, 256 slots each): compacted points of precompute-block b,
// in ascending original index order (deterministic). cnt[b] = #points (vl>0).
// Also zeroes hough/dsum and emits per-block class histograms.
__global__ void precompute_pts(const int* __restrict__ label,
                               const float* __restrict__ vert,
                               float4* __restrict__ ptsA,
                               float4* __restrict__ ptsB,
                               int* __restrict__ cnt,
                               float* __restrict__ blockCounts,
                               float* __restrict__ hough,
                               float* __restrict__ dsum) {
    __shared__ int swtot[4], sn2[4];
    const int tid = threadIdx.x;
    const int i = blockIdx.x * 256 + tid;          // i < NV always (48*256 == NV)
    const int iy = i >> 7;
    const int ix = i & (NVX - 1);
    const int pix = (5 * iy) * WW + 5 * ix;
    const int vl = label[pix];
    const float* base = vert + (size_t)(vl * 3) * HH * WW + pix;
    const float ux = base[0];
    const float uy = base[(size_t)HH * WW];
    const float dist = base[(size_t)2 * HH * WW];

    const bool pos = (vl > 0);
    const int lane = tid & 63, w = tid >> 6;
    unsigned long long mp = __ballot(pos);
    unsigned long long m2 = __ballot(vl == 2);
    int rank = __popcll(mp & ((1ull << lane) - 1ull));
    if (lane == 0) { swtot[w] = __popcll(mp); sn2[w] = __popcll(m2); }
    __syncthreads();
    int off = 0;
    for (int k = 0; k < w; ++k) off += swtot[k];
    if (pos) {
        int p = blockIdx.x * 256 + off + rank;
        ptsA[p] = make_float4((float)(5 * ix), (float)(5 * iy), ux, uy);
        float c2 = (vl == 2) ? 1.0f : 0.0f;
        ptsB[p] = make_float4((vl == 1) ? dist : 0.0f,
                              (vl == 2) ? dist : 0.0f,
                              (vl == 1) ? 1.0f : 0.0f, c2);
    }
    if (tid == 0) {
        int tot = swtot[0] + swtot[1] + swtot[2] + swtot[3];
        int n2 = sn2[0] + sn2[1] + sn2[2] + sn2[3];
        cnt[blockIdx.x] = tot;
        blockCounts[blockIdx.x * NC + 0] = (float)(256 - tot);
        blockCounts[blockIdx.x * NC + 1] = (float)(tot - n2);
        blockCounts[blockIdx.x * NC + 2] = (float)n2;
    }
    // zero accumulation targets (NV = 12288 threads total)
    for (int k = i; k < NC * NB; k += NV) hough[k] = 0.0f;
    if (i < 2 * NB) dsum[i] = 0.0f;
}

// ---------------- kernel 2: voting ----------------
// Squared test: cos>0.5 <=> dot>0 && dot^2 > 0.25*nx. Borderline pairs
// (|s| < nx*2e-5, ~30x the rounding band) recompute the reference's exact
// IEEE sequence -> decisions (hence hough/rois) bit-identical to np.
__global__ void vote(const float4* __restrict__ ptsA,
                     const float4* __restrict__ ptsB,
                     const int* __restrict__ cnt,
                     float* __restrict__ hough,
                     float* __restrict__ dsum) {
    __shared__ float4 shA[256];
    __shared__ float4 shB[256];
    const int tid = threadIdx.x;
    const int p0 = blockIdx.y * 256;
    shA[tid] = ptsA[p0 + tid];
    shB[tid] = ptsB[p0 + tid];
    const int n = cnt[blockIdx.y];

    const int b = blockIdx.x * 256 + tid;
    const float bxf = (float)(4 + 8 * (b % NBX));
    const float byf = (float)(4 + 8 * (b / NBX));
    float h1 = 0.f, h2 = 0.f, d1 = 0.f, d2 = 0.f;
    __syncthreads();

#pragma unroll 4
    for (int j = 0; j < n; ++j) {
        float4 a = shA[j];   // vx, vy, ux, uy
        float4 q = shB[j];   // z1, z2, c1, c2
        float ddx = bxf - a.x;
        float ddy = byf - a.y;
        float nx  = __builtin_fmaf(ddx, ddx, __builtin_fmaf(ddy, ddy, 1e-6f));
        float dot = __builtin_fmaf(ddx, a.z, ddy * a.w);
        float s   = __builtin_fmaf(dot, dot, -0.25f * nx);
        bool v = (dot > 0.0f) & (s > 0.0f);
        if (__builtin_expect((dot > 0.0f) && (fabsf(s) < nx * 2e-5f), 0)) {
            // exact reference op sequence (rare)
            float nxe  = __fadd_rn(__fadd_rn(__fmul_rn(ddx, ddx),
                                             __fmul_rn(ddy, ddy)), 1e-6f);
            float inve = __fdiv_rn(1.0f, __fsqrt_rn(nxe));
            float dote = __fadd_rn(__fmul_rn(ddx, a.z), __fmul_rn(ddy, a.w));
            v = __fmul_rn(dote, inve) > 0.5f;
        }
        float m = v ? 1.0f : 0.0f;
        d1 = __builtin_fmaf(m, q.x, d1);
        d2 = __builtin_fmaf(m, q.y, d2);
        h1 = __builtin_fmaf(m, q.z, h1);
        h2 = __builtin_fmaf(m, q.w, h2);
    }
    if (b < NB) {
        atomicAdd(&hough[NB + b], h1);
        atomicAdd(&hough[2 * NB + b], h2);
        atomicAdd(&dsum[b], d1);
        atomicAdd(&dsum[NB + b], d2);
    }
}

// ---------------- kernel 3: argmax + ROI math (one block per class) ----------------
__global__ void finalize(const float* __restrict__ hough,
                         const float* __restrict__ dsum,
                         const float* __restrict__ blockCounts,
                         const float* __restrict__ meta,
                         const float* __restrict__ extents,
                         float* __restrict__ rois) {
    __shared__ unsigned long long skey[256];
    __shared__ float scnt[256];
    const int tid = threadIdx.x;
    const int c = blockIdx.x;

    float cntv = 0.0f;
    for (int i = tid; i < NPB; i += 256) cntv += blockCounts[i * NC + c];
    scnt[tid] = cntv;

    // packed (value_bits, NB-1-i): max value wins, ties -> smallest index
    unsigned long long best = 0ull;
    for (int i = tid; i < NB; i += 256) {
        float v = hough[c * NB + i];
        unsigned long long key =
            ((unsigned long long)__float_as_uint(v) << 32) |
            (unsigned long long)(unsigned)(NB - 1 - i);
        if (key > best) best = key;
    }
    skey[tid] = best;
    __syncthreads();
    for (int s = 128; s > 0; s >>= 1) {
        if (tid < s) {
            if (skey[tid + s] > skey[tid]) skey[tid] = skey[tid + s];
            scnt[tid] += scnt[tid + s];
        }
        __syncthreads();
    }
    if (tid == 0) {
        float votes = __uint_as_float((unsigned)(skey[0] >> 32));
        int peak = NB - 1 - (int)(skey[0] & 0xffffffffull);
        float ds = (c == 0) ? 0.0f : dsum[(c - 1) * NB + peak];
        float depth = __fdiv_rn(ds, fmaxf(votes, 1.0f));
        float cx = (float)(4 + 8 * (peak % NBX));
        float cy = (float)(4 + 8 * (peak / NBX));
        float cntf = scnt[0];
        float score = __fdiv_rn(votes, fmaxf(cntf, 1.0f));
        int valid = (cntf > 5.0f) && (score > 0.3f);
        float fx = meta[0], fy = meta[4];
        float e0 = extents[c * 3 + 0];
        float e1 = extents[c * 3 + 1];
        float e2 = extents[c * 3 + 2];
        float diag = __fsqrt_rn(__fadd_rn(
            __fadd_rn(__fmul_rn(e0, e0), __fmul_rn(e1, e1)), __fmul_rn(e2, e2)));
        float sz = fmaxf(fabsf(depth), 0.001f);
        float bw = __fdiv_rn(fabsf(__fmul_rn(diag, fx)), sz);
        float bh = __fdiv_rn(fabsf(__fmul_rn(diag, fy)), sz);
        rois[c * 6 + 0] = (float)c;
        rois[c * 6 + 1] = cx - bw * 0.5f;
        rois[c * 6 + 2] = cy - bh * 0.5f;
        rois[c * 6 + 3] = cx + bw * 0.5f;
        rois[c * 6 + 4] = cy + bh * 0.5f;
        rois[c * 6 + 5] = valid ? score : 0.0f;
    }
}

extern "C" void kernel_launch(void* const* d_in, const int* in_sizes, int n_in,
                              void* d_out, int out_size, void* d_ws, size_t ws_size,
                              hipStream_t stream) {
    const int* label = (const int*)d_in[0];
    const float* vert = (const float*)d_in[1];
    const float* meta = (const float*)d_in[2];
    const float* extents = (const float*)d_in[3];
    float* out = (float*)d_out;

    char* ws = (char*)d_ws;
    float4* ptsA = (float4*)ws;                                   // 196608 B
    float4* ptsB = (float4*)(ws + (size_t)NV * 16);               // 196608 B
    float* dsum = (float*)(ws + (size_t)2 * NV * 16);             // 38400 B
    float* blockCounts = (float*)(ws + (size_t)2 * NV * 16 + 2 * NB * 4); // 576 B
    int* cnt = (int*)(ws + (size_t)2 * NV * 16 + 2 * NB * 4 + NPB * NC * 4); // 192 B

    float* hough = out + NC * 6;  // 3*NB floats; rois occupy out[0..17]

    precompute_pts<<<NPB, 256, 0, stream>>>(label, vert, ptsA, ptsB,
                                            cnt, blockCounts, hough, dsum);
    vote<<<dim3(BINBLOCKS, NPB), 256, 0, stream>>>(ptsA, ptsB, cnt, hough, dsum);
    finalize<<<NC, 256, 0, stream>>>(hough, dsum, blockCounts, meta, extents, out);
}